// Round 1
// baseline (1602.745 us; speedup 1.0000x reference)
//
#include <hip/hip_runtime.h>

#define F_IN 128
#define F_OUT 64

__global__ void k_init_deg(float* __restrict__ deg, int n) {
    int i = blockIdx.x * blockDim.x + threadIdx.x;
    if (i < n) deg[i] = 1.0f;  // self-loop weight
}

__global__ void k_deg(const int* __restrict__ colp, const float* __restrict__ ew,
                      float* __restrict__ deg, int e) {
    int i = blockIdx.x * blockDim.x + threadIdx.x;
    if (i < e) atomicAdd(&deg[colp[i]], ew[i]);
}

__global__ void k_dis(float* __restrict__ deg, int n) {
    int i = blockIdx.x * blockDim.x + threadIdx.x;
    if (i < n) {
        float d = deg[i];
        deg[i] = d > 0.0f ? rsqrtf(d) : 0.0f;
    }
}

// 256 threads: 16 rows x 64 cols per block. W (32KB) + X tile (8KB) in LDS.
// Also seeds out with the self-loop term dis[i]^2 * xw[i].
__global__ __launch_bounds__(256) void k_gemm(
        const float* __restrict__ X, const float* __restrict__ W,
        const float* __restrict__ dis, float* __restrict__ xw,
        float* __restrict__ out, int n) {
    __shared__ float Ws[F_IN * F_OUT];  // Ws[k*64 + c]
    __shared__ float Xs[16 * F_IN];
    const int t = threadIdx.x;
    const int row0 = blockIdx.x * 16;

    const float4* W4 = (const float4*)W;
    float4* Ws4 = (float4*)Ws;
    #pragma unroll
    for (int i = t; i < F_IN * F_OUT / 4; i += 256) Ws4[i] = W4[i];

    const float4* X4 = (const float4*)X;  // X row r starts at float4 index r*32
    float4* Xs4 = (float4*)Xs;
    const long tile_base = (long)row0 * (F_IN / 4);
    const long x4_count = (long)n * (F_IN / 4);
    for (int i = t; i < 16 * F_IN / 4; i += 256) {
        long gi = tile_base + i;
        Xs4[i] = (gi < x4_count) ? X4[gi] : make_float4(0.f, 0.f, 0.f, 0.f);
    }
    __syncthreads();

    const int c = t & 63;
    const int r0 = (t >> 6) * 4;
    float a0 = 0.f, a1 = 0.f, a2 = 0.f, a3 = 0.f;
    #pragma unroll 4
    for (int k = 0; k < F_IN; ++k) {
        float wv = Ws[k * F_OUT + c];
        a0 += Xs[(r0 + 0) * F_IN + k] * wv;
        a1 += Xs[(r0 + 1) * F_IN + k] * wv;
        a2 += Xs[(r0 + 2) * F_IN + k] * wv;
        a3 += Xs[(r0 + 3) * F_IN + k] * wv;
    }

    const int gr = row0 + r0;
    float acc[4] = {a0, a1, a2, a3};
    #pragma unroll
    for (int j = 0; j < 4; ++j) {
        int r = gr + j;
        if (r < n) {
            float d = dis[r];
            long idx = (long)r * F_OUT + c;
            xw[idx] = acc[j];
            out[idx] = d * d * acc[j];  // self-loop message
        }
    }
}

// 16 lanes per edge, one float4 (4 features) per lane.
__global__ __launch_bounds__(256) void k_scatter(
        const int* __restrict__ ei, const float* __restrict__ ew,
        const float* __restrict__ dis, const float* __restrict__ xw,
        float* __restrict__ out, int e_cnt) {
    long t = (long)blockIdx.x * 256 + threadIdx.x;
    int e = (int)(t >> 4);
    int sub = (int)(t & 15);
    if (e >= e_cnt) return;
    int row = ei[e];
    int col = ei[e_cnt + e];
    float c = dis[row] * ew[e] * dis[col];
    float4 v = ((const float4*)xw)[(long)row * (F_OUT / 4) + sub];
    float* o = out + (long)col * F_OUT + sub * 4;
    atomicAdd(o + 0, c * v.x);
    atomicAdd(o + 1, c * v.y);
    atomicAdd(o + 2, c * v.z);
    atomicAdd(o + 3, c * v.w);
}

__global__ void k_final(float* __restrict__ out, const float* __restrict__ b, long total) {
    long i = (long)blockIdx.x * blockDim.x + threadIdx.x;
    if (i < total) {
        float v = out[i] + b[i & (F_OUT - 1)];
        out[i] = v > 0.f ? v : 0.f;
    }
}

extern "C" void kernel_launch(void* const* d_in, const int* in_sizes, int n_in,
                              void* d_out, int out_size, void* d_ws, size_t ws_size,
                              hipStream_t stream) {
    const float* X  = (const float*)d_in[0];
    const int*   ei = (const int*)d_in[1];
    const float* ew = (const float*)d_in[2];
    const float* W  = (const float*)d_in[3];
    const float* b  = (const float*)d_in[4];
    float* out = (float*)d_out;

    const int n = in_sizes[0] / F_IN;   // 100000
    const int e = in_sizes[2];          // 1600000

    float* deg = (float*)d_ws;                       // n floats
    float* xw  = deg + (((long)n + 127) & ~127L);    // n*F_OUT floats, 512B aligned

    k_init_deg<<<(n + 255) / 256, 256, 0, stream>>>(deg, n);
    k_deg<<<(e + 255) / 256, 256, 0, stream>>>(ei + e, ew, deg, e);
    k_dis<<<(n + 255) / 256, 256, 0, stream>>>(deg, n);
    k_gemm<<<(n + 15) / 16, 256, 0, stream>>>(X, W, deg, xw, out, n);
    k_scatter<<<((long)e * 16 + 255) / 256, 256, 0, stream>>>(ei, ew, deg, xw, out, e);
    k_final<<<((long)n * F_OUT + 255) / 256, 256, 0, stream>>>(out, b, (long)n * F_OUT);
}

// Round 2
// 484.743 us; speedup vs baseline: 3.3064x; 3.3064x over previous
//
#include <hip/hip_runtime.h>

#define F_IN 128
#define F_OUT 64

// ---- init: deg = 1 (self-loop), hist = 0 ----
__global__ void k_init(float* __restrict__ deg, int* __restrict__ hist, int n) {
    int i = blockIdx.x * blockDim.x + threadIdx.x;
    if (i < n) { deg[i] = 1.0f; hist[i] = 0; }
}

// ---- per-edge: accumulate weighted degree at target + histogram counts ----
__global__ void k_deg_hist(const int* __restrict__ colp, const float* __restrict__ ew,
                           float* __restrict__ deg, int* __restrict__ hist, int e) {
    int i = blockIdx.x * blockDim.x + threadIdx.x;
    if (i < e) {
        int c = colp[i];
        atomicAdd(&deg[c], ew[i]);
        atomicAdd(&hist[c], 1);
    }
}

__global__ void k_dis(float* __restrict__ deg, int n) {
    int i = blockIdx.x * blockDim.x + threadIdx.x;
    if (i < n) {
        float d = deg[i];
        deg[i] = d > 0.0f ? rsqrtf(d) : 0.0f;
    }
}

// ---- scan stage 1: per-block (1024 elems) exclusive scan + block totals ----
__global__ __launch_bounds__(256) void k_scan1(const int* __restrict__ hist,
                                               int* __restrict__ loffs,
                                               int* __restrict__ partials, int n) {
    __shared__ int sdata[256];
    const int t = threadIdx.x;
    const int base = blockIdx.x * 1024 + t * 4;
    int h0 = (base + 0 < n) ? hist[base + 0] : 0;
    int h1 = (base + 1 < n) ? hist[base + 1] : 0;
    int h2 = (base + 2 < n) ? hist[base + 2] : 0;
    int h3 = (base + 3 < n) ? hist[base + 3] : 0;
    int tot = h0 + h1 + h2 + h3;
    sdata[t] = tot;
    __syncthreads();
    // Hillis-Steele inclusive scan over 256 thread totals
    for (int off = 1; off < 256; off <<= 1) {
        int v = (t >= off) ? sdata[t - off] : 0;
        __syncthreads();
        sdata[t] += v;
        __syncthreads();
    }
    int excl = sdata[t] - tot;
    if (base + 0 < n) loffs[base + 0] = excl;
    if (base + 1 < n) loffs[base + 1] = excl + h0;
    if (base + 2 < n) loffs[base + 2] = excl + h0 + h1;
    if (base + 3 < n) loffs[base + 3] = excl + h0 + h1 + h2;
    if (t == 255) partials[blockIdx.x] = sdata[255];
}

// ---- scan stage 2: exclusive scan of block totals (tiny, single thread) ----
__global__ void k_scan2(int* __restrict__ partials, int nb) {
    if (blockIdx.x == 0 && threadIdx.x == 0) {
        int run = 0;
        for (int i = 0; i < nb; ++i) { int v = partials[i]; partials[i] = run; run += v; }
    }
}

// ---- scan stage 3: final offsets + cursor copy ----
__global__ void k_scan3(const int* __restrict__ loffs, const int* __restrict__ partials,
                        int* __restrict__ offsets, int* __restrict__ cursor, int n, int e) {
    int i = blockIdx.x * blockDim.x + threadIdx.x;
    if (i < n) {
        int off = loffs[i] + partials[i >> 10];
        offsets[i] = off;
        cursor[i] = off;
    }
    if (i == 0) offsets[n] = e;
}

// ---- CSR fill: sort edges by target, precompute norm ----
__global__ void k_csr_fill(const int* __restrict__ ei, const float* __restrict__ ew,
                           const float* __restrict__ dis, int* __restrict__ cursor,
                           int2* __restrict__ edata, int e) {
    int i = blockIdx.x * blockDim.x + threadIdx.x;
    if (i < e) {
        int row = ei[i];
        int col = ei[e + i];
        float nrm = dis[row] * ew[i] * dis[col];
        int pos = atomicAdd(&cursor[col], 1);
        edata[pos] = make_int2(row, __float_as_int(nrm));
    }
}

// ---- GEMM: xw = X @ W (f32, LDS-tiled) ----
__global__ __launch_bounds__(256) void k_gemm(
        const float* __restrict__ X, const float* __restrict__ W,
        float* __restrict__ xw, int n) {
    __shared__ float Ws[F_IN * F_OUT];  // Ws[k*64 + c]
    __shared__ float Xs[16 * F_IN];
    const int t = threadIdx.x;
    const int row0 = blockIdx.x * 16;

    const float4* W4 = (const float4*)W;
    float4* Ws4 = (float4*)Ws;
    #pragma unroll
    for (int i = t; i < F_IN * F_OUT / 4; i += 256) Ws4[i] = W4[i];

    const float4* X4 = (const float4*)X;
    float4* Xs4 = (float4*)Xs;
    const long tile_base = (long)row0 * (F_IN / 4);
    const long x4_count = (long)n * (F_IN / 4);
    for (int i = t; i < 16 * F_IN / 4; i += 256) {
        long gi = tile_base + i;
        Xs4[i] = (gi < x4_count) ? X4[gi] : make_float4(0.f, 0.f, 0.f, 0.f);
    }
    __syncthreads();

    const int c = t & 63;
    const int r0 = (t >> 6) * 4;
    float a0 = 0.f, a1 = 0.f, a2 = 0.f, a3 = 0.f;
    #pragma unroll 4
    for (int k = 0; k < F_IN; ++k) {
        float wv = Ws[k * F_OUT + c];
        a0 += Xs[(r0 + 0) * F_IN + k] * wv;
        a1 += Xs[(r0 + 1) * F_IN + k] * wv;
        a2 += Xs[(r0 + 2) * F_IN + k] * wv;
        a3 += Xs[(r0 + 3) * F_IN + k] * wv;
    }

    const int gr = row0 + r0;
    float acc[4] = {a0, a1, a2, a3};
    #pragma unroll
    for (int j = 0; j < 4; ++j) {
        int r = gr + j;
        if (r < n) xw[(long)r * F_OUT + c] = acc[j];
    }
}

// ---- gather: one wave per node, lane = output feature ----
__global__ __launch_bounds__(256) void k_gather(
        const int* __restrict__ offsets, const int2* __restrict__ edata,
        const float* __restrict__ dis, const float* __restrict__ xw,
        const float* __restrict__ b, float* __restrict__ out, int n) {
    int node = blockIdx.x * 4 + (threadIdx.x >> 6);
    int lane = threadIdx.x & 63;
    if (node >= n) return;
    int beg = offsets[node];
    int end = offsets[node + 1];
    float di = dis[node];
    float acc = di * di * xw[(long)node * F_OUT + lane];  // self-loop message
    int j = beg;
    for (; j + 1 < end; j += 2) {
        int2 e0 = edata[j];
        int2 e1 = edata[j + 1];
        float v0 = xw[(long)e0.x * F_OUT + lane];
        float v1 = xw[(long)e1.x * F_OUT + lane];
        acc += __int_as_float(e0.y) * v0;
        acc += __int_as_float(e1.y) * v1;
    }
    if (j < end) {
        int2 e0 = edata[j];
        acc += __int_as_float(e0.y) * xw[(long)e0.x * F_OUT + lane];
    }
    float v = acc + b[lane];
    out[(long)node * F_OUT + lane] = v > 0.f ? v : 0.f;
}

extern "C" void kernel_launch(void* const* d_in, const int* in_sizes, int n_in,
                              void* d_out, int out_size, void* d_ws, size_t ws_size,
                              hipStream_t stream) {
    const float* X  = (const float*)d_in[0];
    const int*   ei = (const int*)d_in[1];
    const float* ew = (const float*)d_in[2];
    const float* W  = (const float*)d_in[3];
    const float* b  = (const float*)d_in[4];
    float* out = (float*)d_out;

    const int n = in_sizes[0] / F_IN;   // 100000
    const int e = in_sizes[2];          // 1600000

    // workspace layout (all 4-byte elems; keep 8B alignment for edata)
    long p = 0;
    auto alloc = [&](long cnt) { long off = p; p += (cnt + 63) & ~63L; return off; };
    char* ws = (char*)d_ws;
    float* deg     = (float*)(ws + 4 * alloc(n));
    int*   hist    = (int*)  (ws + 4 * alloc(n));
    int*   loffs   = (int*)  (ws + 4 * alloc(n));
    int*   partials= (int*)  (ws + 4 * alloc(1024));
    int*   offsets = (int*)  (ws + 4 * alloc(n + 1));
    int*   cursor  = (int*)  (ws + 4 * alloc(n));
    int2*  edata   = (int2*) (ws + 4 * alloc(2L * e));
    float* xw      = (float*)(ws + 4 * alloc((long)n * F_OUT));

    const int nb = (n + 1023) / 1024;

    k_init<<<(n + 255) / 256, 256, 0, stream>>>(deg, hist, n);
    k_deg_hist<<<(e + 255) / 256, 256, 0, stream>>>(ei + e, ew, deg, hist, e);
    k_dis<<<(n + 255) / 256, 256, 0, stream>>>(deg, n);
    k_scan1<<<nb, 256, 0, stream>>>(hist, loffs, partials, n);
    k_scan2<<<1, 64, 0, stream>>>(partials, nb);
    k_scan3<<<(n + 255) / 256, 256, 0, stream>>>(loffs, partials, offsets, cursor, n, e);
    k_csr_fill<<<(e + 255) / 256, 256, 0, stream>>>(ei, ew, deg, cursor, edata, e);
    k_gemm<<<(n + 15) / 16, 256, 0, stream>>>(X, W, xw, n);
    k_gather<<<(n + 3) / 4, 256, 0, stream>>>(offsets, edata, deg, xw, b, out, n);
}

// Round 3
// 337.329 us; speedup vs baseline: 4.7513x; 1.4370x over previous
//
#include <hip/hip_runtime.h>

#define F_IN 128
#define F_OUT 64

#define FIX_BITS 42
#define FIX_MASK ((1ULL << FIX_BITS) - 1ULL)
#define Q 1048576.0f  // 2^20

__device__ inline ushort f2bf(float f) {
    unsigned u = __float_as_uint(f);
    unsigned r = u + 0x7fff + ((u >> 16) & 1);
    return (ushort)(r >> 16);
}
__device__ inline float bf2f(ushort u) {
    return __uint_as_float(((unsigned)u) << 16);
}

// ---- init: packed = deg 1.0 in Q20 fixed, count 0 ----
__global__ void k_init(unsigned long long* __restrict__ packed, int n) {
    int i = blockIdx.x * blockDim.x + threadIdx.x;
    if (i < n) packed[i] = (unsigned long long)(1u << 20);
}

// ---- per-edge: single u64 atomic = deg sum (fixed) + count; old count = rank ----
__global__ void k_edge1(const int* __restrict__ colp, const float* __restrict__ ew,
                        unsigned long long* __restrict__ packed,
                        int* __restrict__ rank, int e) {
    int i = blockIdx.x * blockDim.x + threadIdx.x;
    if (i < e) {
        int c = colp[i];
        unsigned long long add = (1ULL << FIX_BITS) +
            (unsigned long long)__float2uint_rn(ew[i] * Q);
        unsigned long long old = atomicAdd(&packed[c], add);
        rank[i] = (int)(old >> FIX_BITS);
    }
}

// ---- unpack: dis = rsqrt(deg), hist = count ----
__global__ void k_dis(const unsigned long long* __restrict__ packed,
                      float* __restrict__ dis, int* __restrict__ hist, int n) {
    int i = blockIdx.x * blockDim.x + threadIdx.x;
    if (i < n) {
        unsigned long long p = packed[i];
        float d = (float)(p & FIX_MASK) * (1.0f / Q);
        dis[i] = d > 0.0f ? rsqrtf(d) : 0.0f;
        hist[i] = (int)(p >> FIX_BITS);
    }
}

// ---- scan stage 1: per-block (1024 elems) exclusive scan + block totals ----
__global__ __launch_bounds__(256) void k_scan1(const int* __restrict__ hist,
                                               int* __restrict__ loffs,
                                               int* __restrict__ partials, int n) {
    __shared__ int sdata[256];
    const int t = threadIdx.x;
    const int base = blockIdx.x * 1024 + t * 4;
    int h0 = (base + 0 < n) ? hist[base + 0] : 0;
    int h1 = (base + 1 < n) ? hist[base + 1] : 0;
    int h2 = (base + 2 < n) ? hist[base + 2] : 0;
    int h3 = (base + 3 < n) ? hist[base + 3] : 0;
    int tot = h0 + h1 + h2 + h3;
    sdata[t] = tot;
    __syncthreads();
    for (int off = 1; off < 256; off <<= 1) {
        int v = (t >= off) ? sdata[t - off] : 0;
        __syncthreads();
        sdata[t] += v;
        __syncthreads();
    }
    int excl = sdata[t] - tot;
    if (base + 0 < n) loffs[base + 0] = excl;
    if (base + 1 < n) loffs[base + 1] = excl + h0;
    if (base + 2 < n) loffs[base + 2] = excl + h0 + h1;
    if (base + 3 < n) loffs[base + 3] = excl + h0 + h1 + h2;
    if (t == 255) partials[blockIdx.x] = sdata[255];
}

__global__ void k_scan2(int* __restrict__ partials, int nb) {
    if (blockIdx.x == 0 && threadIdx.x == 0) {
        int run = 0;
        for (int i = 0; i < nb; ++i) { int v = partials[i]; partials[i] = run; run += v; }
    }
}

__global__ void k_scan3(const int* __restrict__ loffs, const int* __restrict__ partials,
                        int* __restrict__ offsets, int n, int e) {
    int i = blockIdx.x * blockDim.x + threadIdx.x;
    if (i < n) offsets[i] = loffs[i] + partials[i >> 10];
    if (i == 0) offsets[n] = e;
}

// ---- place edges (NO atomics): pos = offsets[col] + rank ----
__global__ void k_place(const int* __restrict__ ei, const float* __restrict__ ew,
                        const float* __restrict__ dis, const int* __restrict__ rank,
                        const int* __restrict__ offsets, int2* __restrict__ edata, int e) {
    int i = blockIdx.x * blockDim.x + threadIdx.x;
    if (i < e) {
        int row = ei[i];
        int col = ei[e + i];
        float nrm = dis[row] * ew[i] * dis[col];
        int pos = offsets[col] + rank[i];
        edata[pos] = make_int2(row, __float_as_int(nrm));
    }
}

// ---- GEMM: xw = X @ W (f32 compute, bf16 store) ----
__global__ __launch_bounds__(256) void k_gemm(
        const float* __restrict__ X, const float* __restrict__ W,
        ushort* __restrict__ xwb, int n) {
    __shared__ float Ws[F_IN * F_OUT];
    __shared__ float Xs[16 * F_IN];
    const int t = threadIdx.x;
    const int row0 = blockIdx.x * 16;

    const float4* W4 = (const float4*)W;
    float4* Ws4 = (float4*)Ws;
    #pragma unroll
    for (int i = t; i < F_IN * F_OUT / 4; i += 256) Ws4[i] = W4[i];

    const float4* X4 = (const float4*)X;
    float4* Xs4 = (float4*)Xs;
    const long tile_base = (long)row0 * (F_IN / 4);
    const long x4_count = (long)n * (F_IN / 4);
    for (int i = t; i < 16 * F_IN / 4; i += 256) {
        long gi = tile_base + i;
        Xs4[i] = (gi < x4_count) ? X4[gi] : make_float4(0.f, 0.f, 0.f, 0.f);
    }
    __syncthreads();

    const int c = t & 63;
    const int r0 = (t >> 6) * 4;
    float a0 = 0.f, a1 = 0.f, a2 = 0.f, a3 = 0.f;
    #pragma unroll 4
    for (int k = 0; k < F_IN; ++k) {
        float wv = Ws[k * F_OUT + c];
        a0 += Xs[(r0 + 0) * F_IN + k] * wv;
        a1 += Xs[(r0 + 1) * F_IN + k] * wv;
        a2 += Xs[(r0 + 2) * F_IN + k] * wv;
        a3 += Xs[(r0 + 3) * F_IN + k] * wv;
    }

    const int gr = row0 + r0;
    float acc[4] = {a0, a1, a2, a3};
    #pragma unroll
    for (int j = 0; j < 4; ++j) {
        int r = gr + j;
        if (r < n) xwb[(long)r * F_OUT + c] = f2bf(acc[j]);
    }
}

// ---- gather: one wave per node, lane = output feature, bf16 xw rows ----
__global__ __launch_bounds__(256) void k_gather(
        const int* __restrict__ offsets, const int2* __restrict__ edata,
        const float* __restrict__ dis, const ushort* __restrict__ xwb,
        const float* __restrict__ b, float* __restrict__ out, int n) {
    int node = blockIdx.x * 4 + (threadIdx.x >> 6);
    int lane = threadIdx.x & 63;
    if (node >= n) return;
    int beg = offsets[node];
    int end = offsets[node + 1];
    float di = dis[node];
    float acc = di * di * bf2f(xwb[(long)node * F_OUT + lane]);
    int j = beg;
    for (; j + 3 < end; j += 4) {
        int2 e0 = edata[j], e1 = edata[j + 1], e2 = edata[j + 2], e3 = edata[j + 3];
        float v0 = bf2f(xwb[(long)e0.x * F_OUT + lane]);
        float v1 = bf2f(xwb[(long)e1.x * F_OUT + lane]);
        float v2 = bf2f(xwb[(long)e2.x * F_OUT + lane]);
        float v3 = bf2f(xwb[(long)e3.x * F_OUT + lane]);
        acc += __int_as_float(e0.y) * v0 + __int_as_float(e1.y) * v1
             + __int_as_float(e2.y) * v2 + __int_as_float(e3.y) * v3;
    }
    for (; j < end; ++j) {
        int2 e0 = edata[j];
        acc += __int_as_float(e0.y) * bf2f(xwb[(long)e0.x * F_OUT + lane]);
    }
    float v = acc + b[lane];
    out[(long)node * F_OUT + lane] = v > 0.f ? v : 0.f;
}

extern "C" void kernel_launch(void* const* d_in, const int* in_sizes, int n_in,
                              void* d_out, int out_size, void* d_ws, size_t ws_size,
                              hipStream_t stream) {
    const float* X  = (const float*)d_in[0];
    const int*   ei = (const int*)d_in[1];
    const float* ew = (const float*)d_in[2];
    const float* W  = (const float*)d_in[3];
    const float* b  = (const float*)d_in[4];
    float* out = (float*)d_out;

    const int n = in_sizes[0] / F_IN;   // 100000
    const int e = in_sizes[2];          // 1600000

    // workspace layout (4-byte units, 256B-aligned chunks)
    long p = 0;
    auto alloc = [&](long cnt) { long off = p; p += (cnt + 63) & ~63L; return off; };
    char* ws = (char*)d_ws;
    unsigned long long* packed = (unsigned long long*)(ws + 4 * alloc(2L * n));
    int*   rank    = (int*)  (ws + 4 * alloc(e));
    int*   hist    = (int*)  (ws + 4 * alloc(n));
    int*   loffs   = (int*)  (ws + 4 * alloc(n));
    int*   partials= (int*)  (ws + 4 * alloc(1024));
    int*   offsets = (int*)  (ws + 4 * alloc(n + 1));
    float* dis     = (float*)(ws + 4 * alloc(n));
    int2*  edata   = (int2*) (ws + 4 * alloc(2L * e));
    ushort* xwb    = (ushort*)(ws + 4 * alloc((long)n * F_OUT / 2));

    const int nb = (n + 1023) / 1024;

    k_init<<<(n + 255) / 256, 256, 0, stream>>>(packed, n);
    k_edge1<<<(e + 255) / 256, 256, 0, stream>>>(ei + e, ew, packed, rank, e);
    k_dis<<<(n + 255) / 256, 256, 0, stream>>>(packed, dis, hist, n);
    k_scan1<<<nb, 256, 0, stream>>>(hist, loffs, partials, n);
    k_scan2<<<1, 64, 0, stream>>>(partials, nb);
    k_scan3<<<(n + 255) / 256, 256, 0, stream>>>(loffs, partials, offsets, n, e);
    k_place<<<(e + 255) / 256, 256, 0, stream>>>(ei, ew, dis, rank, offsets, edata, e);
    k_gemm<<<(n + 15) / 16, 256, 0, stream>>>(X, W, xwb, n);
    k_gather<<<(n + 3) / 4, 256, 0, stream>>>(offsets, edata, dis, xwb, b, out, n);
}

// Round 4
// 291.712 us; speedup vs baseline: 5.4943x; 1.1564x over previous
//
#include <hip/hip_runtime.h>

#define F_IN 128
#define F_OUT 64
#define FIX_BITS 42
#define FIX_MASK ((1ULL << FIX_BITS) - 1ULL)
#define QF 1048576.0f  // 2^20

typedef __bf16 bf16x8 __attribute__((ext_vector_type(8)));
typedef float f32x4 __attribute__((ext_vector_type(4)));

__device__ inline ushort f2bf(float f) {
    unsigned u = __float_as_uint(f);
    unsigned r = u + 0x7fff + ((u >> 16) & 1);
    return (ushort)(r >> 16);
}
__device__ inline float bf2f_lo(unsigned u) { return __uint_as_float(u << 16); }
__device__ inline float bf2f_hi(unsigned u) { return __uint_as_float(u & 0xffff0000u); }

#define LDS_STRIDE 136  // 128 + 8 ushorts: keeps 16B align (272B rows), spreads banks

// ---- mega: blocks [0, nb_gemm) do bf16-MFMA GEMM; rest do the edge atomic pass ----
__global__ __launch_bounds__(256) void k_mega(
        const float* __restrict__ X, const float* __restrict__ W,
        const int* __restrict__ colp, const float* __restrict__ ew,
        unsigned long long* __restrict__ packed, int* __restrict__ rank,
        ushort* __restrict__ xwb, int n, int e, int nb_gemm) {
    __shared__ ushort Xs[64 * LDS_STRIDE];
    __shared__ ushort Wt[64 * LDS_STRIDE];
    const int t = threadIdx.x;

    if ((int)blockIdx.x >= nb_gemm) {
        // ---- edge pass: one u64 atomic = Q20 deg sum + count; old count = rank ----
        int i = ((int)blockIdx.x - nb_gemm) * 256 + t;
        if (i < e) {
            int c = colp[i];
            unsigned long long add = (1ULL << FIX_BITS) +
                (unsigned long long)__float2uint_rn(ew[i] * QF);
            unsigned long long old = atomicAdd(&packed[c], add);
            rank[i] = (int)(old >> FIX_BITS);
        }
        return;
    }

    // ---- GEMM: 64 rows x 64 cols, K=128, mfma_f32_16x16x32_bf16 ----
    const int row0 = (int)blockIdx.x * 64;
    const float4* X4 = (const float4*)X;
    const long x4max = (long)n * (F_IN / 4);
    #pragma unroll
    for (int i = 0; i < 8; ++i) {
        long gi = (long)row0 * (F_IN / 4) + t + i * 256;  // coalesced
        float4 v = (gi < x4max) ? X4[gi] : make_float4(0.f, 0.f, 0.f, 0.f);
        int flat = (t + i * 256) * 4;
        int r = flat >> 7, k = flat & 127;
        ushort4 pv = make_ushort4(f2bf(v.x), f2bf(v.y), f2bf(v.z), f2bf(v.w));
        *(ushort4*)&Xs[r * LDS_STRIDE + k] = pv;
    }
    const float4* W4 = (const float4*)W;
    #pragma unroll
    for (int i = 0; i < 8; ++i) {
        int idx = t + i * 256;  // 2048 float4s = 128x64 W
        float4 v = W4[idx];
        int flat = idx * 4;
        int k = flat >> 6, c = flat & 63;
        Wt[(c + 0) * LDS_STRIDE + k] = f2bf(v.x);
        Wt[(c + 1) * LDS_STRIDE + k] = f2bf(v.y);
        Wt[(c + 2) * LDS_STRIDE + k] = f2bf(v.z);
        Wt[(c + 3) * LDS_STRIDE + k] = f2bf(v.w);
    }
    __syncthreads();

    const int w = t >> 6, lane = t & 63;
    const int m16 = lane & 15, quad = lane >> 4;
    f32x4 acc[4] = {{0,0,0,0},{0,0,0,0},{0,0,0,0},{0,0,0,0}};
    #pragma unroll
    for (int kk = 0; kk < 4; ++kk) {
        bf16x8 a = *(const bf16x8*)&Xs[(w * 16 + m16) * LDS_STRIDE + kk * 32 + quad * 8];
        #pragma unroll
        for (int nt = 0; nt < 4; ++nt) {
            bf16x8 bb = *(const bf16x8*)&Wt[(nt * 16 + m16) * LDS_STRIDE + kk * 32 + quad * 8];
            acc[nt] = __builtin_amdgcn_mfma_f32_16x16x32_bf16(a, bb, acc[nt], 0, 0, 0);
        }
    }
    #pragma unroll
    for (int nt = 0; nt < 4; ++nt) {
        #pragma unroll
        for (int reg = 0; reg < 4; ++reg) {
            int gr = row0 + w * 16 + quad * 4 + reg;  // C/D: row=quad*4+reg, col=lane&15
            if (gr < n) xwb[(long)gr * F_OUT + nt * 16 + m16] = f2bf(acc[nt][reg]);
        }
    }
}

// ---- scan1 (+ dis unpack): per-1024-node block scan ----
__global__ __launch_bounds__(256) void k_scan1(
        const unsigned long long* __restrict__ packed, float* __restrict__ dis,
        int* __restrict__ loffs, int* __restrict__ partials, int n) {
    __shared__ int sdata[256];
    const int t = threadIdx.x;
    const int base = blockIdx.x * 1024 + t * 4;
    int h[4];
    #pragma unroll
    for (int q = 0; q < 4; ++q) {
        int i = base + q;
        if (i < n) {
            unsigned long long p = packed[i];
            h[q] = (int)(p >> FIX_BITS);
            float d = (float)(p & FIX_MASK) * (1.0f / QF) + 1.0f;  // +1 self-loop
            dis[i] = rsqrtf(d);
        } else h[q] = 0;
    }
    int tot = h[0] + h[1] + h[2] + h[3];
    sdata[t] = tot;
    __syncthreads();
    for (int off = 1; off < 256; off <<= 1) {
        int v = (t >= off) ? sdata[t - off] : 0;
        __syncthreads();
        sdata[t] += v;
        __syncthreads();
    }
    int excl = sdata[t] - tot;
    if (base + 0 < n) loffs[base + 0] = excl;
    if (base + 1 < n) loffs[base + 1] = excl + h[0];
    if (base + 2 < n) loffs[base + 2] = excl + h[0] + h[1];
    if (base + 3 < n) loffs[base + 3] = excl + h[0] + h[1] + h[2];
    if (t == 255) partials[blockIdx.x] = sdata[255];
}

// ---- scan2: exclusive scan of <=256 block partials, one block ----
__global__ __launch_bounds__(256) void k_scan2(int* __restrict__ partials, int nb) {
    __shared__ int s[256];
    int t = threadIdx.x;
    int v = (t < nb) ? partials[t] : 0;
    s[t] = v;
    __syncthreads();
    for (int off = 1; off < 256; off <<= 1) {
        int x = (t >= off) ? s[t - off] : 0;
        __syncthreads();
        s[t] += x;
        __syncthreads();
    }
    if (t < nb) partials[t] = s[t] - v;
}

// ---- place: pos = offsets(col) + rank (NO atomics); edata = row<<15 | bf15(norm) ----
__global__ __launch_bounds__(256) void k_place(
        const int* __restrict__ ei, const float* __restrict__ ew,
        const float* __restrict__ dis, const int* __restrict__ rank,
        const int* __restrict__ loffs, const int* __restrict__ partials,
        unsigned* __restrict__ edata, int e) {
    int i = blockIdx.x * 256 + threadIdx.x;
    if (i >= e) return;
    int row = ei[i], col = ei[e + i];
    float nrm = dis[row] * ew[i] * dis[col];  // >= 0
    unsigned u = __float_as_uint(nrm);
    unsigned r = u + 0x7fff + ((u >> 16) & 1);
    unsigned nb15 = (r >> 16) & 0x7fffu;
    int pos = loffs[col] + partials[col >> 10] + rank[i];
    edata[pos] = ((unsigned)row << 15) | nb15;
}

// ---- gather: wave per node; half-waves take alternate edges; lane = feature pair ----
__global__ __launch_bounds__(256) void k_gather(
        const int* __restrict__ loffs, const int* __restrict__ partials,
        const unsigned* __restrict__ edata, const float* __restrict__ dis,
        const unsigned* __restrict__ xw32, const float* __restrict__ b,
        float* __restrict__ out, int n, int e) {
    int node = blockIdx.x * 4 + (threadIdx.x >> 6);
    if (node >= n) return;
    int lane = threadIdx.x & 63;
    int half = lane >> 5, fl = lane & 31;
    int beg = loffs[node] + partials[node >> 10];
    int end = (node + 1 < n) ? (loffs[node + 1] + partials[(node + 1) >> 10]) : e;
    float a0 = 0.f, a1 = 0.f;
    if (half == 0) {
        float di = dis[node];
        unsigned xv = xw32[(long)node * 32 + fl];
        float s = di * di;
        a0 = s * bf2f_lo(xv);
        a1 = s * bf2f_hi(xv);
    }
    int j = beg + half;
    for (; j + 2 < end; j += 4) {
        unsigned v0 = edata[j], v1 = edata[j + 2];
        unsigned x0 = xw32[(long)(v0 >> 15) * 32 + fl];
        unsigned x1 = xw32[(long)(v1 >> 15) * 32 + fl];
        float n0 = __uint_as_float((v0 & 0x7fffu) << 16);
        float n1 = __uint_as_float((v1 & 0x7fffu) << 16);
        a0 += n0 * bf2f_lo(x0) + n1 * bf2f_lo(x1);
        a1 += n0 * bf2f_hi(x0) + n1 * bf2f_hi(x1);
    }
    if (j < end) {
        unsigned v0 = edata[j];
        unsigned x0 = xw32[(long)(v0 >> 15) * 32 + fl];
        float n0 = __uint_as_float((v0 & 0x7fffu) << 16);
        a0 += n0 * bf2f_lo(x0);
        a1 += n0 * bf2f_hi(x0);
    }
    a0 += __shfl_down(a0, 32);
    a1 += __shfl_down(a1, 32);
    if (half == 0) {
        float f0 = a0 + b[2 * fl];
        float f1 = a1 + b[2 * fl + 1];
        ((float2*)out)[(long)node * 32 + fl] =
            make_float2(f0 > 0.f ? f0 : 0.f, f1 > 0.f ? f1 : 0.f);
    }
}

extern "C" void kernel_launch(void* const* d_in, const int* in_sizes, int n_in,
                              void* d_out, int out_size, void* d_ws, size_t ws_size,
                              hipStream_t stream) {
    const float* X  = (const float*)d_in[0];
    const int*   ei = (const int*)d_in[1];
    const float* ew = (const float*)d_in[2];
    const float* W  = (const float*)d_in[3];
    const float* b  = (const float*)d_in[4];
    float* out = (float*)d_out;

    const int n = in_sizes[0] / F_IN;   // 100000
    const int e = in_sizes[2];          // 1600000

    long p = 0;
    auto alloc = [&](long cnt) { long off = p; p += (cnt + 63) & ~63L; return off; };
    char* ws = (char*)d_ws;
    unsigned long long* packed = (unsigned long long*)(ws + 4 * alloc(2L * n));
    int*      rank     = (int*)     (ws + 4 * alloc(e));
    int*      loffs    = (int*)     (ws + 4 * alloc(n));
    int*      partials = (int*)     (ws + 4 * alloc(256));
    float*    dis      = (float*)   (ws + 4 * alloc(n));
    unsigned* edata    = (unsigned*)(ws + 4 * alloc(e));
    ushort*   xwb      = (ushort*)  (ws + 4 * alloc((long)n * F_OUT / 2));

    const int nb_gemm = (n + 63) / 64;
    const int nb_edge = (e + 255) / 256;
    const int nbp = (n + 1023) / 1024;  // 98 <= 256

    hipMemsetAsync(packed, 0, (size_t)n * 8, stream);
    k_mega<<<nb_gemm + nb_edge, 256, 0, stream>>>(X, W, ei + e, ew, packed, rank,
                                                  xwb, n, e, nb_gemm);
    k_scan1<<<nbp, 256, 0, stream>>>(packed, dis, loffs, partials, n);
    k_scan2<<<1, 256, 0, stream>>>(partials, nbp);
    k_place<<<nb_edge, 256, 0, stream>>>(ei, ew, dis, rank, loffs, partials, edata, e);
    k_gather<<<(n + 3) / 4, 256, 0, stream>>>(loffs, partials, edata, dis,
                                              (const unsigned*)xwb, b, out, n, e);
}